// Round 1
// baseline (301.016 us; speedup 1.0000x reference)
//
#include <hip/hip_runtime.h>
#include <hip/hip_bf16.h>
#include <math.h>

// ---- problem constants (hardcoded in reference) ----
#define NMETA  4
#define NNODE  871
#define NFEAT  512
#define XDIM   (116*116)            // 13456
#define ZPLANE (NNODE*NFEAT)        // 445952
#define Z4     (ZPLANE/4)           // 111488
#define NCHUNK 55                   // ceil(871/16)

// ---- workspace layout (float offsets) ----
#define WS_SCORES 0                 // [4]
#define WS_COEF   4                 // [4]  (1+attn)
#define WS_GAMMA  8                 // [1]  0.1*sum(attn)
#define WS_XH     16                // [512] raw x@xp_w (no bias)
#define WS_C1     528               // [512] xh_full@w1[:512] + b1
#define WS_E1     1040              // [871*512] emb@w1[512:]
#define WS_H2     (WS_E1 + ZPLANE)  // [871*256]
#define WS_V      (WS_H2 + NNODE*256) // [871] mlp(t0) per row

__global__ void k_init(float* __restrict__ ws) {
  int t = blockIdx.x * 256 + threadIdx.x;
  if (t < 1056) ws[t] = 0.f;   // zero scores/gamma/xh atomic targets
}

// scores[p] = sum_i sum_f tanh(W[i]*z[p,i,f]+b[i])*q[i,f]   (1/N applied later)
__global__ void k_scores(const float* __restrict__ z, const float* __restrict__ W,
                         const float* __restrict__ b, const float* __restrict__ q,
                         float* __restrict__ ws) {
  const int p = blockIdx.x / NCHUNK;
  const int chunk = blockIdx.x % NCHUNK;
  const int i0 = chunk * 16;
  const int i1 = min(i0 + 16, NNODE);
  const int tid = threadIdx.x;
  float local = 0.f;
  for (int i = i0; i < i1; ++i) {
    const float wi = W[i];
    const float bi = b[i];
    const float* zr = z + ((size_t)p * NNODE + i) * NFEAT;
    const float* qr = q + (size_t)i * NFEAT;
    for (int f = tid; f < NFEAT; f += 256)
      local += tanhf(wi * zr[f] + bi) * qr[f];
  }
  __shared__ float red[256];
  red[tid] = local;
  __syncthreads();
  for (int s = 128; s > 0; s >>= 1) {
    if (tid < s) red[tid] += red[tid + s];
    __syncthreads();
  }
  if (tid == 0) atomicAdd(&ws[WS_SCORES + p], red[0]);
}

// attn = softmax(scores / sum(scores)); coef = 1+attn; gamma term
__global__ void k_attn(float* __restrict__ ws) {
  if (threadIdx.x == 0) {
    float s[NMETA], sum = 0.f;
    for (int p = 0; p < NMETA; ++p) { s[p] = ws[WS_SCORES + p] / (float)NNODE; sum += s[p]; }
    float prop[NMETA], m = -1e30f;
    for (int p = 0; p < NMETA; ++p) { prop[p] = s[p] / sum; m = fmaxf(m, prop[p]); }
    float e[NMETA], es = 0.f;
    for (int p = 0; p < NMETA; ++p) { e[p] = expf(prop[p] - m); es += e[p]; }
    float asum = 0.f;
    for (int p = 0; p < NMETA; ++p) {
      float a = e[p] / es;
      ws[WS_COEF + p] = 1.f + a;
      asum += a;
    }
    ws[WS_GAMMA] = 0.1f * asum;
  }
}

// emb[i,f] = sum_p coef[p]*z[p,i,f]  -> written straight to d_out (fp32)
__global__ void k_emb(const float* __restrict__ z, const float* __restrict__ ws,
                      float* __restrict__ emb_out) {
  const int idx = blockIdx.x * 256 + threadIdx.x;
  if (idx >= Z4) return;
  const float c0 = ws[WS_COEF + 0], c1 = ws[WS_COEF + 1];
  const float c2 = ws[WS_COEF + 2], c3 = ws[WS_COEF + 3];
  const float4* z4 = (const float4*)z;
  float4 a = z4[idx];
  float4 b = z4[Z4 + idx];
  float4 c = z4[2 * Z4 + idx];
  float4 d = z4[3 * Z4 + idx];
  float4 r;
  r.x = c0 * a.x + c1 * b.x + c2 * c.x + c3 * d.x;
  r.y = c0 * a.y + c1 * b.y + c2 * c.y + c3 * d.y;
  r.z = c0 * a.z + c1 * b.z + c2 * c.z + c3 * d.z;
  r.w = c0 * a.w + c1 * b.w + c2 * c.w + c3 * d.w;
  ((float4*)emb_out)[idx] = r;
}

// xh[f] = sum_d x[d]*xp_w[d,f]   (vector-matrix; bias added in k_c1)
// grid: 8 f-tiles x 16 d-splits; block 256 = 64 f-lanes x 4 d-groups
__global__ void k_xh(const float* __restrict__ x, const float* __restrict__ xpw,
                     float* __restrict__ xh) {
  const int ft = blockIdx.x % 8;
  const int ds = blockIdx.x / 8;
  const int lane = threadIdx.x & 63;
  const int dp = threadIdx.x >> 6;
  const int f = ft * 64 + lane;
  const int dstart = ds * 841;
  const int dend = min(dstart + 841, XDIM);
  float acc = 0.f;
  for (int d = dstart + dp; d < dend; d += 4)
    acc += x[d] * xpw[(size_t)d * NFEAT + f];
  __shared__ float red[256];
  red[threadIdx.x] = acc;
  __syncthreads();
  if (dp == 0)
    atomicAdd(&xh[f], red[lane] + red[64 + lane] + red[128 + lane] + red[192 + lane]);
}

// c1[j] = b1[j] + sum_f (xh[f]+xp_b[f]) * w1[f, j]    (w1 rows 0..511)
__global__ void k_c1(const float* __restrict__ xh, const float* __restrict__ xpb,
                     const float* __restrict__ w1, const float* __restrict__ b1,
                     float* __restrict__ c1) {
  const int lane = threadIdx.x & 63;
  const int fg = threadIdx.x >> 6;
  const int j = blockIdx.x * 64 + lane;
  float acc = 0.f;
  for (int f = fg; f < NFEAT; f += 4)
    acc += (xh[f] + xpb[f]) * w1[(size_t)f * NFEAT + j];
  __shared__ float red[256];
  red[threadIdx.x] = acc;
  __syncthreads();
  if (fg == 0)
    c1[j] = b1[j] + red[lane] + red[64 + lane] + red[128 + lane] + red[192 + lane];
}

// E1 = emb[871x512] @ w1[512:1024, :512]   32x32 tile, 2x2 micro
__global__ void k_gemmE1(const float* __restrict__ A, const float* __restrict__ w1,
                         float* __restrict__ C) {
  __shared__ float As[32][33];
  __shared__ float Bs[32][33];
  const int tid = threadIdx.x;
  const int tn = tid & 15, tm = tid >> 4;
  const float* Bbase = w1 + (size_t)NFEAT * NFEAT;   // rows 512..1023
  float acc00 = 0.f, acc01 = 0.f, acc10 = 0.f, acc11 = 0.f;
  for (int k0 = 0; k0 < NFEAT; k0 += 32) {
    for (int l = tid; l < 1024; l += 256) {
      int r = l >> 5, c = l & 31;
      int gr = blockIdx.x * 32 + r;
      As[r][c] = (gr < NNODE) ? A[(size_t)gr * NFEAT + k0 + c] : 0.f;
      Bs[r][c] = Bbase[(size_t)(k0 + r) * NFEAT + blockIdx.y * 32 + c];
    }
    __syncthreads();
#pragma unroll
    for (int k = 0; k < 32; ++k) {
      float a0 = As[2 * tm + 0][k], a1 = As[2 * tm + 1][k];
      float b0 = Bs[k][2 * tn + 0], b1 = Bs[k][2 * tn + 1];
      acc00 += a0 * b0; acc01 += a0 * b1;
      acc10 += a1 * b0; acc11 += a1 * b1;
    }
    __syncthreads();
  }
  int gr0 = blockIdx.x * 32 + 2 * tm;
  int gc0 = blockIdx.y * 32 + 2 * tn;
  if (gr0 < NNODE)     { C[(size_t)gr0 * NFEAT + gc0] = acc00; C[(size_t)gr0 * NFEAT + gc0 + 1] = acc01; }
  if (gr0 + 1 < NNODE) { C[(size_t)(gr0+1) * NFEAT + gc0] = acc10; C[(size_t)(gr0+1) * NFEAT + gc0 + 1] = acc11; }
}

// H2 = relu( relu(E1 + c1) @ w2 + b2 )   [871x512]@[512x256]
__global__ void k_gemmH2(const float* __restrict__ E1, const float* __restrict__ c1,
                         const float* __restrict__ w2, const float* __restrict__ b2,
                         float* __restrict__ H2) {
  __shared__ float As[32][33];
  __shared__ float Bs[32][33];
  const int tid = threadIdx.x;
  const int tn = tid & 15, tm = tid >> 4;
  float acc00 = 0.f, acc01 = 0.f, acc10 = 0.f, acc11 = 0.f;
  for (int k0 = 0; k0 < NFEAT; k0 += 32) {
    for (int l = tid; l < 1024; l += 256) {
      int r = l >> 5, c = l & 31;
      int gr = blockIdx.x * 32 + r;
      As[r][c] = (gr < NNODE) ? fmaxf(E1[(size_t)gr * NFEAT + k0 + c] + c1[k0 + c], 0.f) : 0.f;
      Bs[r][c] = w2[(size_t)(k0 + r) * 256 + blockIdx.y * 32 + c];
    }
    __syncthreads();
#pragma unroll
    for (int k = 0; k < 32; ++k) {
      float a0 = As[2 * tm + 0][k], a1 = As[2 * tm + 1][k];
      float b0 = Bs[k][2 * tn + 0], b1 = Bs[k][2 * tn + 1];
      acc00 += a0 * b0; acc01 += a0 * b1;
      acc10 += a1 * b0; acc11 += a1 * b1;
    }
    __syncthreads();
  }
  int gr0 = blockIdx.x * 32 + 2 * tm;
  int gc0 = blockIdx.y * 32 + 2 * tn;
  if (gr0 < NNODE) {
    H2[(size_t)gr0 * 256 + gc0]     = fmaxf(acc00 + b2[gc0], 0.f);
    H2[(size_t)gr0 * 256 + gc0 + 1] = fmaxf(acc01 + b2[gc0 + 1], 0.f);
  }
  if (gr0 + 1 < NNODE) {
    H2[(size_t)(gr0+1) * 256 + gc0]     = fmaxf(acc10 + b2[gc0], 0.f);
    H2[(size_t)(gr0+1) * 256 + gc0 + 1] = fmaxf(acc11 + b2[gc0 + 1], 0.f);
  }
}

// v[i] = b3 + H2[i,:] . w3      (one 64-lane wave per row)
__global__ void k_rowdot(const float* __restrict__ H2, const float* __restrict__ w3,
                         const float* __restrict__ b3, float* __restrict__ v) {
  const int wid = (blockIdx.x * 256 + threadIdx.x) >> 6;
  const int lane = threadIdx.x & 63;
  if (wid >= NNODE) return;
  float acc = 0.f;
  for (int j = lane; j < 256; j += 64) acc += H2[(size_t)wid * 256 + j] * w3[j];
  for (int off = 32; off > 0; off >>= 1) acc += __shfl_down(acc, off);
  if (lane == 0) v[wid] = acc + b3[0];
}

// loss = max(mean(v) - log(mean(exp(v))+1e-8), 0) + 0.1*sum(attn)
__global__ void k_final(const float* __restrict__ ws, float* __restrict__ out) {
  const float* v = ws + WS_V;
  float s0 = 0.f, s1 = 0.f;
  for (int i = threadIdx.x; i < NNODE; i += 256) {
    float x = v[i];
    s0 += x;
    s1 += expf(x);
  }
  __shared__ float r0[256], r1[256];
  r0[threadIdx.x] = s0; r1[threadIdx.x] = s1;
  __syncthreads();
  for (int s = 128; s > 0; s >>= 1) {
    if (threadIdx.x < s) {
      r0[threadIdx.x] += r0[threadIdx.x + s];
      r1[threadIdx.x] += r1[threadIdx.x + s];
    }
    __syncthreads();
  }
  if (threadIdx.x == 0) {
    float m0 = r0[0] / (float)NNODE;
    float m1 = r1[0] / (float)NNODE;
    float mi = m0 - logf(m1 + 1e-8f);
    out[ZPLANE] = fmaxf(mi, 0.f) + ws[WS_GAMMA];
  }
}

extern "C" void kernel_launch(void* const* d_in, const int* in_sizes, int n_in,
                              void* d_out, int out_size, void* d_ws, size_t ws_size,
                              hipStream_t stream) {
  const float* z   = (const float*)d_in[0];
  const float* x   = (const float*)d_in[1];
  const float* W   = (const float*)d_in[2];
  const float* b   = (const float*)d_in[3];
  const float* q   = (const float*)d_in[4];
  const float* xpw = (const float*)d_in[5];
  const float* xpb = (const float*)d_in[6];
  const float* w1  = (const float*)d_in[7];
  const float* b1  = (const float*)d_in[8];
  const float* w2  = (const float*)d_in[9];
  const float* b2  = (const float*)d_in[10];
  const float* w3  = (const float*)d_in[11];
  const float* b3  = (const float*)d_in[12];
  // d_in[13] (perm) intentionally unused: xh is identical for every row, so
  // mlp(t1)[i] == mlp(t0)[perm[i]] exactly => mean(exp(mlp(t1))) == mean(exp(mlp(t0))).
  float* out = (float*)d_out;
  float* ws  = (float*)d_ws;

  k_init<<<5, 256, 0, stream>>>(ws);
  k_scores<<<NMETA * NCHUNK, 256, 0, stream>>>(z, W, b, q, ws);
  k_attn<<<1, 64, 0, stream>>>(ws);
  k_emb<<<(Z4 + 255) / 256, 256, 0, stream>>>(z, ws, out);
  k_xh<<<128, 256, 0, stream>>>(x, xpw, ws + WS_XH);
  k_c1<<<8, 256, 0, stream>>>(ws + WS_XH, xpb, w1, b1, ws + WS_C1);
  dim3 g7(28, 16);
  k_gemmE1<<<g7, 256, 0, stream>>>(out, w1, ws + WS_E1);
  dim3 g8(28, 8);
  k_gemmH2<<<g8, 256, 0, stream>>>(ws + WS_E1, ws + WS_C1, w2, b2, ws + WS_H2);
  k_rowdot<<<(NNODE + 3) / 4, 256, 0, stream>>>(ws + WS_H2, w3, b3, ws + WS_V);
  k_final<<<1, 256, 0, stream>>>(ws, out);
}

// Round 2
// 211.387 us; speedup vs baseline: 1.4240x; 1.4240x over previous
//
#include <hip/hip_runtime.h>
#include <hip/hip_bf16.h>
#include <math.h>

// ---- problem constants (hardcoded in reference) ----
#define NMETA  4
#define NNODE  871
#define NFEAT  512
#define XDIM   (116*116)            // 13456
#define ZPLANE (NNODE*NFEAT)        // 445952
#define Z4     (ZPLANE/4)           // 111488
#define NCHUNK 55                   // ceil(871/16)
#define MPAD   896                  // 56*16 (M padded to MFMA tiles)
#define MT     56                   // M tiles of 16

// ---- workspace layout (float offsets) ----
#define WS_SCORES 0                 // [4]
#define WS_COEF   4                 // [4]  (1+attn)
#define WS_GAMMA  8                 // [1]  0.1*sum(attn)
#define WS_XH     16                // [512] raw x@xp_w (no bias)
#define WS_C1     528               // [512] xh_full@w1[:512] + b1
#define WS_E1     1040              // [896*512] fp32 emb@w1[512:] (pad rows = 0)
#define WS_EMBB   (WS_E1 + MPAD*NFEAT)     // 459792: bf16 [896][512] (ALIASES H2 region)
#define WS_H2     WS_EMBB                  // fp32 [871][256]; written only after EMBB is dead
#define WS_V      (WS_EMBB + MPAD*NFEAT/2) // 689168: [871]
#define WS_W1P    690040            // packed bf16 w1[512:1024] -> 512*512/2 floats
#define WS_W2P    (WS_W1P + 512*512/2)     // 821112: packed bf16 w2 -> 512*256/2 floats

typedef short v8s __attribute__((ext_vector_type(8)));
typedef float v4f __attribute__((ext_vector_type(4)));

static __device__ __forceinline__ short f2bf(float f) {
  __hip_bfloat16 h = __float2bfloat16(f);
  return *reinterpret_cast<short*>(&h);
}

// zero atomic targets + bf16-emb pad rows (871..895)
__global__ void k_init(float* __restrict__ ws) {
  int t = blockIdx.x * 256 + threadIdx.x;
  if (t < 1056) ws[t] = 0.f;
  else if (t < 1056 + (MPAD - NNODE) * NFEAT / 2)
    ws[WS_EMBB + NNODE * NFEAT / 2 + (t - 1056)] = 0.f;
}

// scores[p] = sum_i sum_f tanh(W[i]*z[p,i,f]+b[i])*q[i,f]
__global__ void k_scores(const float* __restrict__ z, const float* __restrict__ W,
                         const float* __restrict__ b, const float* __restrict__ q,
                         float* __restrict__ ws) {
  const int p = blockIdx.x / NCHUNK;
  const int chunk = blockIdx.x % NCHUNK;
  const int i0 = chunk * 16;
  const int i1 = min(i0 + 16, NNODE);
  const int tid = threadIdx.x;
  float local = 0.f;
  for (int i = i0; i < i1; ++i) {
    const float wi = W[i];
    const float bi = b[i];
    const float* zr = z + ((size_t)p * NNODE + i) * NFEAT;
    const float* qr = q + (size_t)i * NFEAT;
    for (int f = tid; f < NFEAT; f += 256)
      local += tanhf(wi * zr[f] + bi) * qr[f];
  }
  __shared__ float red[256];
  red[tid] = local;
  __syncthreads();
  for (int s = 128; s > 0; s >>= 1) {
    if (tid < s) red[tid] += red[tid + s];
    __syncthreads();
  }
  if (tid == 0) atomicAdd(&ws[WS_SCORES + p], red[0]);
}

__global__ void k_attn(float* __restrict__ ws) {
  if (threadIdx.x == 0) {
    float s[NMETA], sum = 0.f;
    for (int p = 0; p < NMETA; ++p) { s[p] = ws[WS_SCORES + p] / (float)NNODE; sum += s[p]; }
    float prop[NMETA], m = -1e30f;
    for (int p = 0; p < NMETA; ++p) { prop[p] = s[p] / sum; m = fmaxf(m, prop[p]); }
    float e[NMETA], es = 0.f;
    for (int p = 0; p < NMETA; ++p) { e[p] = expf(prop[p] - m); es += e[p]; }
    float asum = 0.f;
    for (int p = 0; p < NMETA; ++p) {
      float a = e[p] / es;
      ws[WS_COEF + p] = 1.f + a;
      asum += a;
    }
    ws[WS_GAMMA] = 0.1f * asum;
  }
}

// emb = sum_p coef[p]*z[p] -> fp32 to d_out AND bf16 (row-major) to ws for MFMA
__global__ void k_emb(const float* __restrict__ z, const float* __restrict__ ws,
                      float* __restrict__ emb_out, short* __restrict__ embb) {
  const int idx = blockIdx.x * 256 + threadIdx.x;
  if (idx >= Z4) return;
  const float c0 = ws[WS_COEF + 0], c1 = ws[WS_COEF + 1];
  const float c2 = ws[WS_COEF + 2], c3 = ws[WS_COEF + 3];
  const float4* z4 = (const float4*)z;
  float4 a = z4[idx];
  float4 b = z4[Z4 + idx];
  float4 c = z4[2 * Z4 + idx];
  float4 d = z4[3 * Z4 + idx];
  float4 r;
  r.x = c0 * a.x + c1 * b.x + c2 * c.x + c3 * d.x;
  r.y = c0 * a.y + c1 * b.y + c2 * c.y + c3 * d.y;
  r.z = c0 * a.z + c1 * b.z + c2 * c.z + c3 * d.z;
  r.w = c0 * a.w + c1 * b.w + c2 * c.w + c3 * d.w;
  ((float4*)emb_out)[idx] = r;
  short4 h;
  h.x = f2bf(r.x); h.y = f2bf(r.y); h.z = f2bf(r.z); h.w = f2bf(r.w);
  ((short4*)embb)[idx] = h;
}

// xh[f] = sum_d x[d]*xp_w[d,f] — float4 streams, x staged in LDS, unroll for MLP
__global__ __launch_bounds__(256) void k_xh(const float* __restrict__ x,
                                            const float* __restrict__ xpw,
                                            float* __restrict__ xh) {
  const int f4 = threadIdx.x & 127;     // float4 column index (f = 4*f4)
  const int rp = threadIdx.x >> 7;      // row parity 0/1
  const int d0 = blockIdx.x * 106;
  const int rows = min(106, XDIM - d0); // may be <=0 for last block
  __shared__ float xs[106];
  if ((int)threadIdx.x < rows) xs[threadIdx.x] = x[d0 + threadIdx.x];
  __syncthreads();
  float4 acc = {0.f, 0.f, 0.f, 0.f};
  const float4* xp4 = (const float4*)xpw;
#pragma unroll 4
  for (int r = rp; r < rows; r += 2) {
    const float xv = xs[r];
    const float4 w = xp4[(size_t)(d0 + r) * 128 + f4];
    acc.x += xv * w.x; acc.y += xv * w.y; acc.z += xv * w.z; acc.w += xv * w.w;
  }
  __shared__ float4 red[128];
  if (rp) red[f4] = acc;
  __syncthreads();
  if (!rp) {
    float4 o = red[f4];
    atomicAdd(&xh[f4 * 4 + 0], acc.x + o.x);
    atomicAdd(&xh[f4 * 4 + 1], acc.y + o.y);
    atomicAdd(&xh[f4 * 4 + 2], acc.z + o.z);
    atomicAdd(&xh[f4 * 4 + 3], acc.w + o.w);
  }
}

// pack w1[512:1024] and w2 into MFMA B-fragment order (bf16):
// idx(kb,nt,quad,n15,j) = (((kb*NT+nt)*4+quad)*16+n15)*8+j holds B[kb*32+quad*8+j][nt*16+n15]
__global__ void k_conv(const float* __restrict__ w1, const float* __restrict__ w2,
                       short* __restrict__ w1p, short* __restrict__ w2p) {
  int t = blockIdx.x * 256 + threadIdx.x;
  if (t < 512 * 512) {
    int j = t & 7; int r = t >> 3;
    int n15 = r & 15; r >>= 4;
    int quad = r & 3; r >>= 2;
    int nt = r & 31; int kb = r >> 5;       // NT=32
    int k = kb * 32 + quad * 8 + j;
    int n = nt * 16 + n15;
    w1p[t] = f2bf(w1[(size_t)(512 + k) * 512 + n]);
  } else if (t < 512 * 512 + 512 * 256) {
    int o = t - 512 * 512;
    int j = o & 7; int r = o >> 3;
    int n15 = r & 15; r >>= 4;
    int quad = r & 3; r >>= 2;
    int nt = r & 15; int kb = r >> 4;       // NT=16
    int k = kb * 32 + quad * 8 + j;
    int n = nt * 16 + n15;
    w2p[o] = f2bf(w2[(size_t)k * 256 + n]);
  }
}

// c1[j] = b1[j] + sum_f (xh[f]+xp_b[f]) * w1[f, j]
__global__ void k_c1(const float* __restrict__ xh, const float* __restrict__ xpb,
                     const float* __restrict__ w1, const float* __restrict__ b1,
                     float* __restrict__ c1) {
  const int lane = threadIdx.x & 63;
  const int fg = threadIdx.x >> 6;
  const int j = blockIdx.x * 64 + lane;
  float acc = 0.f;
  for (int f = fg; f < NFEAT; f += 4)
    acc += (xh[f] + xpb[f]) * w1[(size_t)f * NFEAT + j];
  __shared__ float red[256];
  red[threadIdx.x] = acc;
  __syncthreads();
  if (fg == 0)
    c1[j] = b1[j] + red[lane] + red[64 + lane] + red[128 + lane] + red[192 + lane];
}

// E1[896x512] = embb(bf16) @ w1p(bf16)  via mfma_f32_16x16x32_bf16
// wave = one 16x64 C tile; 448 waves = 112 blocks
__global__ __launch_bounds__(256) void k_gemmE1(const short* __restrict__ embb,
                                                const short* __restrict__ w1p,
                                                float* __restrict__ E1) {
  const int lane = threadIdx.x & 63;
  const int wid = blockIdx.x * 4 + (threadIdx.x >> 6);
  const int n15 = lane & 15, quad = lane >> 4;
  const int mt = wid % MT;          // 0..55
  const int ng = wid / MT;          // 0..7
  const short* A = embb + (size_t)(mt * 16 + n15) * NFEAT + quad * 8;
  const short* Bbase = w1p + (ng * 16 + quad) * 128 + n15 * 8;
  v4f acc0 = {0.f,0.f,0.f,0.f}, acc1 = acc0, acc2 = acc0, acc3 = acc0;
#pragma unroll
  for (int kb = 0; kb < 16; ++kb) {
    v8s a = *(const v8s*)(A + kb * 32);
    const short* Bp = Bbase + (size_t)kb * 16384;   // kb*NT(32)*4*16*8
    v8s b0 = *(const v8s*)(Bp);
    v8s b1 = *(const v8s*)(Bp + 512);
    v8s b2 = *(const v8s*)(Bp + 1024);
    v8s b3 = *(const v8s*)(Bp + 1536);
    acc0 = __builtin_amdgcn_mfma_f32_16x16x32_bf16(a, b0, acc0, 0, 0, 0);
    acc1 = __builtin_amdgcn_mfma_f32_16x16x32_bf16(a, b1, acc1, 0, 0, 0);
    acc2 = __builtin_amdgcn_mfma_f32_16x16x32_bf16(a, b2, acc2, 0, 0, 0);
    acc3 = __builtin_amdgcn_mfma_f32_16x16x32_bf16(a, b3, acc3, 0, 0, 0);
  }
  float* C0 = E1 + (size_t)(mt * 16 + quad * 4) * NFEAT + ng * 64 + n15;
#pragma unroll
  for (int r = 0; r < 4; ++r) {
    C0[(size_t)r * NFEAT +  0] = acc0[r];
    C0[(size_t)r * NFEAT + 16] = acc1[r];
    C0[(size_t)r * NFEAT + 32] = acc2[r];
    C0[(size_t)r * NFEAT + 48] = acc3[r];
  }
}

// H2[871x256] = relu( relu(E1+c1)(bf16 on the fly) @ w2p + b2 )
// wave = 16x64 C tile; 224 waves = 56 blocks
__global__ __launch_bounds__(256) void k_gemmH2(const float* __restrict__ E1,
                                                const float* __restrict__ c1,
                                                const short* __restrict__ w2p,
                                                const float* __restrict__ b2,
                                                float* __restrict__ H2) {
  const int lane = threadIdx.x & 63;
  const int wid = blockIdx.x * 4 + (threadIdx.x >> 6);
  const int n15 = lane & 15, quad = lane >> 4;
  const int mt = wid % MT;          // 0..55
  const int ng = wid / MT;          // 0..3
  const float* Arow = E1 + (size_t)(mt * 16 + n15) * NFEAT + quad * 8;
  const short* Bbase = w2p + (ng * 16 + quad) * 128 + n15 * 8;
  v4f acc0 = {0.f,0.f,0.f,0.f}, acc1 = acc0, acc2 = acc0, acc3 = acc0;
#pragma unroll
  for (int kb = 0; kb < 16; ++kb) {
    float4 e0 = *(const float4*)(Arow + kb * 32);
    float4 e1 = *(const float4*)(Arow + kb * 32 + 4);
    float4 ca = *(const float4*)(c1 + kb * 32 + quad * 8);
    float4 cb = *(const float4*)(c1 + kb * 32 + quad * 8 + 4);
    v8s a;
    a[0] = f2bf(fmaxf(e0.x + ca.x, 0.f));
    a[1] = f2bf(fmaxf(e0.y + ca.y, 0.f));
    a[2] = f2bf(fmaxf(e0.z + ca.z, 0.f));
    a[3] = f2bf(fmaxf(e0.w + ca.w, 0.f));
    a[4] = f2bf(fmaxf(e1.x + cb.x, 0.f));
    a[5] = f2bf(fmaxf(e1.y + cb.y, 0.f));
    a[6] = f2bf(fmaxf(e1.z + cb.z, 0.f));
    a[7] = f2bf(fmaxf(e1.w + cb.w, 0.f));
    const short* Bp = Bbase + (size_t)kb * 8192;    // kb*NT(16)*4*16*8
    v8s b0 = *(const v8s*)(Bp);
    v8s b1 = *(const v8s*)(Bp + 512);
    v8s b2v = *(const v8s*)(Bp + 1024);
    v8s b3 = *(const v8s*)(Bp + 1536);
    acc0 = __builtin_amdgcn_mfma_f32_16x16x32_bf16(a, b0, acc0, 0, 0, 0);
    acc1 = __builtin_amdgcn_mfma_f32_16x16x32_bf16(a, b1, acc1, 0, 0, 0);
    acc2 = __builtin_amdgcn_mfma_f32_16x16x32_bf16(a, b2v, acc2, 0, 0, 0);
    acc3 = __builtin_amdgcn_mfma_f32_16x16x32_bf16(a, b3, acc3, 0, 0, 0);
  }
  const int grow0 = mt * 16 + quad * 4;
  const float bb0 = b2[ng * 64 + n15], bb1 = b2[ng * 64 + 16 + n15];
  const float bb2 = b2[ng * 64 + 32 + n15], bb3 = b2[ng * 64 + 48 + n15];
#pragma unroll
  for (int r = 0; r < 4; ++r) {
    const int grow = grow0 + r;
    if (grow < NNODE) {
      float* Hr = H2 + (size_t)grow * 256 + ng * 64 + n15;
      Hr[0]  = fmaxf(acc0[r] + bb0, 0.f);
      Hr[16] = fmaxf(acc1[r] + bb1, 0.f);
      Hr[32] = fmaxf(acc2[r] + bb2, 0.f);
      Hr[48] = fmaxf(acc3[r] + bb3, 0.f);
    }
  }
}

// v[i] = b3 + H2[i,:] . w3
__global__ void k_rowdot(const float* __restrict__ H2, const float* __restrict__ w3,
                         const float* __restrict__ b3, float* __restrict__ v) {
  const int wid = (blockIdx.x * 256 + threadIdx.x) >> 6;
  const int lane = threadIdx.x & 63;
  if (wid >= NNODE) return;
  float acc = 0.f;
  for (int j = lane; j < 256; j += 64) acc += H2[(size_t)wid * 256 + j] * w3[j];
  for (int off = 32; off > 0; off >>= 1) acc += __shfl_down(acc, off);
  if (lane == 0) v[wid] = acc + b3[0];
}

// loss = max(mean(v) - log(mean(exp(v))+1e-8), 0) + 0.1*sum(attn)
__global__ void k_final(const float* __restrict__ ws, float* __restrict__ out) {
  const float* v = ws + WS_V;
  float s0 = 0.f, s1 = 0.f;
  for (int i = threadIdx.x; i < NNODE; i += 256) {
    float x = v[i];
    s0 += x;
    s1 += expf(x);
  }
  __shared__ float r0[256], r1[256];
  r0[threadIdx.x] = s0; r1[threadIdx.x] = s1;
  __syncthreads();
  for (int s = 128; s > 0; s >>= 1) {
    if (threadIdx.x < s) {
      r0[threadIdx.x] += r0[threadIdx.x + s];
      r1[threadIdx.x] += r1[threadIdx.x + s];
    }
    __syncthreads();
  }
  if (threadIdx.x == 0) {
    float m0 = r0[0] / (float)NNODE;
    float m1 = r1[0] / (float)NNODE;
    float mi = m0 - logf(m1 + 1e-8f);
    out[ZPLANE] = fmaxf(mi, 0.f) + ws[WS_GAMMA];
  }
}

extern "C" void kernel_launch(void* const* d_in, const int* in_sizes, int n_in,
                              void* d_out, int out_size, void* d_ws, size_t ws_size,
                              hipStream_t stream) {
  const float* z   = (const float*)d_in[0];
  const float* x   = (const float*)d_in[1];
  const float* W   = (const float*)d_in[2];
  const float* b   = (const float*)d_in[3];
  const float* q   = (const float*)d_in[4];
  const float* xpw = (const float*)d_in[5];
  const float* xpb = (const float*)d_in[6];
  const float* w1  = (const float*)d_in[7];
  const float* b1  = (const float*)d_in[8];
  const float* w2  = (const float*)d_in[9];
  const float* b2  = (const float*)d_in[10];
  const float* w3  = (const float*)d_in[11];
  const float* b3  = (const float*)d_in[12];
  // d_in[13] (perm) unused: xh identical per row => permutation invariant under mean(exp(.)).
  float* out = (float*)d_out;
  float* ws  = (float*)d_ws;

  short* embb = (short*)(ws + WS_EMBB);
  short* w1p  = (short*)(ws + WS_W1P);
  short* w2p  = (short*)(ws + WS_W2P);

  k_init<<<30, 256, 0, stream>>>(ws);
  k_xh<<<128, 256, 0, stream>>>(x, xpw, ws + WS_XH);
  k_conv<<<1536, 256, 0, stream>>>(w1, w2, w1p, w2p);
  k_scores<<<NMETA * NCHUNK, 256, 0, stream>>>(z, W, b, q, ws);
  k_attn<<<1, 64, 0, stream>>>(ws);
  k_emb<<<(Z4 + 255) / 256, 256, 0, stream>>>(z, ws, out, embb);
  k_c1<<<8, 256, 0, stream>>>(ws + WS_XH, xpb, w1, b1, ws + WS_C1);
  k_gemmE1<<<112, 256, 0, stream>>>(embb, w1p, ws + WS_E1);
  k_gemmH2<<<56, 256, 0, stream>>>(ws + WS_E1, ws + WS_C1, w2p, b2, ws + WS_H2);
  k_rowdot<<<(NNODE + 3) / 4, 256, 0, stream>>>(ws + WS_H2, w3, b3, ws + WS_V);
  k_final<<<1, 256, 0, stream>>>(ws, out);
}

// Round 3
// 153.850 us; speedup vs baseline: 1.9566x; 1.3740x over previous
//
#include <hip/hip_runtime.h>
#include <hip/hip_bf16.h>
#include <math.h>

// ---- problem constants (hardcoded in reference) ----
#define NMETA  4
#define NNODE  871
#define NFEAT  512
#define XDIM   (116*116)            // 13456
#define ZPLANE (NNODE*NFEAT)        // 445952
#define Z4     (ZPLANE/4)           // 111488
#define NCHUNK 55                   // ceil(871/16)
#define MPAD   896                  // 56*16 (M padded to MFMA tiles)
#define MT     56                   // M tiles of 16

// ---- workspace layout (float offsets) ----
#define WS_SCORES 0                 // [4]
#define WS_C1     528               // [512] (xh_full@w1[:512]) + b1, atomic target
#define WS_E1     1040              // [896*512] fp32 emb@w1[512:]
#define WS_XHP    WS_E1             // ALIAS: [128*512] xh partials; dead before gemmE1 writes E1
#define WS_EMBB   (WS_E1 + MPAD*NFEAT)     // 459792: bf16 [896][512] (ALIASES H2 region)
#define WS_H2     WS_EMBB                  // fp32 [871][256]; written only after EMBB is dead
#define WS_V      (WS_EMBB + MPAD*NFEAT/2) // 689168: [871]
#define WS_W1P    690040            // packed bf16 w1[512:1024] -> 512*512/2 floats
#define WS_W2P    (WS_W1P + 512*512/2)     // 821112: packed bf16 w2 -> 512*256/2 floats

typedef short v8s __attribute__((ext_vector_type(8)));
typedef float v4f __attribute__((ext_vector_type(4)));

static __device__ __forceinline__ short f2bf(float f) {
  __hip_bfloat16 h = __float2bfloat16(f);
  return *reinterpret_cast<short*>(&h);
}

// coef[p] = 1 + softmax(scores/N / sum(scores/N))[p]  — recomputed per block, ~30 flops
static __device__ __forceinline__ void compute_coef(const float* __restrict__ ws, float* coef) {
  float s[NMETA], sum = 0.f;
#pragma unroll
  for (int p = 0; p < NMETA; ++p) { s[p] = ws[WS_SCORES + p] / (float)NNODE; sum += s[p]; }
  float prop[NMETA], m = -1e30f;
#pragma unroll
  for (int p = 0; p < NMETA; ++p) { prop[p] = s[p] / sum; m = fmaxf(m, prop[p]); }
  float e[NMETA], es = 0.f;
#pragma unroll
  for (int p = 0; p < NMETA; ++p) { e[p] = expf(prop[p] - m); es += e[p]; }
#pragma unroll
  for (int p = 0; p < NMETA; ++p) coef[p] = 1.f + e[p] / es;
}

// zero atomic targets (scores, c1) + bf16-emb pad rows (871..895)
__global__ void k_init(float* __restrict__ ws) {
  int t = blockIdx.x * 256 + threadIdx.x;
  if (t < 1040) ws[t] = 0.f;
  else if (t < 1040 + (MPAD - NNODE) * NFEAT / 2)
    ws[WS_EMBB + NNODE * NFEAT / 2 + (t - 1040)] = 0.f;
}

// scores[p] = sum_i sum_f tanh(W[i]*z[p,i,f]+b[i])*q[i,f]  — float4 streams
__global__ void k_scores(const float* __restrict__ z, const float* __restrict__ W,
                         const float* __restrict__ b, const float* __restrict__ q,
                         float* __restrict__ ws) {
  const int p = blockIdx.x / NCHUNK;
  const int chunk = blockIdx.x % NCHUNK;
  const int i0 = chunk * 16;
  const int i1 = min(i0 + 16, NNODE);
  const int f4 = threadIdx.x & 127;
  const int ip = threadIdx.x >> 7;
  float local = 0.f;
  for (int i = i0 + ip; i < i1; i += 2) {
    const float wi = W[i];
    const float bi = b[i];
    const float4 zr = ((const float4*)(z + ((size_t)p * NNODE + i) * NFEAT))[f4];
    const float4 qr = ((const float4*)(q + (size_t)i * NFEAT))[f4];
    local += tanhf(wi * zr.x + bi) * qr.x + tanhf(wi * zr.y + bi) * qr.y
           + tanhf(wi * zr.z + bi) * qr.z + tanhf(wi * zr.w + bi) * qr.w;
  }
  __shared__ float red[256];
  red[threadIdx.x] = local;
  __syncthreads();
  for (int s = 128; s > 0; s >>= 1) {
    if ((int)threadIdx.x < s) red[threadIdx.x] += red[threadIdx.x + s];
    __syncthreads();
  }
  if (threadIdx.x == 0) atomicAdd(&ws[WS_SCORES + p], red[0]);
}

// emb = sum_p coef[p]*z[p] -> fp32 to d_out AND bf16 (row-major) to ws for MFMA
__global__ void k_emb(const float* __restrict__ z, const float* __restrict__ ws,
                      float* __restrict__ emb_out, short* __restrict__ embb) {
  const int idx = blockIdx.x * 256 + threadIdx.x;
  if (idx >= Z4) return;
  float coef[NMETA];
  compute_coef(ws, coef);
  const float4* z4 = (const float4*)z;
  float4 a = z4[idx];
  float4 b = z4[Z4 + idx];
  float4 c = z4[2 * Z4 + idx];
  float4 d = z4[3 * Z4 + idx];
  float4 r;
  r.x = coef[0] * a.x + coef[1] * b.x + coef[2] * c.x + coef[3] * d.x;
  r.y = coef[0] * a.y + coef[1] * b.y + coef[2] * c.y + coef[3] * d.y;
  r.z = coef[0] * a.z + coef[1] * b.z + coef[2] * c.z + coef[3] * d.z;
  r.w = coef[0] * a.w + coef[1] * b.w + coef[2] * c.w + coef[3] * d.w;
  ((float4*)emb_out)[idx] = r;
  short4 h;
  h.x = f2bf(r.x); h.y = f2bf(r.y); h.z = f2bf(r.z); h.w = f2bf(r.w);
  ((short4*)embb)[idx] = h;
}

// xh partials: xhp[blk][f] = sum_{d in blk} x[d]*xp_w[d,f]  — NO atomics
__global__ __launch_bounds__(256) void k_xh(const float* __restrict__ x,
                                            const float* __restrict__ xpw,
                                            float* __restrict__ xhp) {
  const int f4 = threadIdx.x & 127;     // float4 column index (f = 4*f4)
  const int rp = threadIdx.x >> 7;      // row parity 0/1
  const int d0 = blockIdx.x * 106;
  const int rows = min(106, XDIM - d0);
  __shared__ float xs[106];
  if ((int)threadIdx.x < rows) xs[threadIdx.x] = x[d0 + threadIdx.x];
  __syncthreads();
  float4 acc = {0.f, 0.f, 0.f, 0.f};
  const float4* xp4 = (const float4*)xpw;
#pragma unroll 4
  for (int r = rp; r < rows; r += 2) {
    const float xv = xs[r];
    const float4 w = xp4[(size_t)(d0 + r) * 128 + f4];
    acc.x += xv * w.x; acc.y += xv * w.y; acc.z += xv * w.z; acc.w += xv * w.w;
  }
  __shared__ float4 red[128];
  if (rp) red[f4] = acc;
  __syncthreads();
  if (!rp) {
    float4 o = red[f4];
    o.x += acc.x; o.y += acc.y; o.z += acc.z; o.w += acc.w;
    ((float4*)(xhp + (size_t)blockIdx.x * NFEAT))[f4] = o;
  }
}

// pack w1[512:1024] and w2 into MFMA B-fragment order (bf16)
__global__ void k_conv(const float* __restrict__ w1, const float* __restrict__ w2,
                       short* __restrict__ w1p, short* __restrict__ w2p) {
  int t = blockIdx.x * 256 + threadIdx.x;
  if (t < 512 * 512) {
    int j = t & 7; int r = t >> 3;
    int n15 = r & 15; r >>= 4;
    int quad = r & 3; r >>= 2;
    int nt = r & 31; int kb = r >> 5;       // NT=32
    int k = kb * 32 + quad * 8 + j;
    int n = nt * 16 + n15;
    w1p[t] = f2bf(w1[(size_t)(512 + k) * 512 + n]);
  } else if (t < 512 * 512 + 512 * 256) {
    int o = t - 512 * 512;
    int j = o & 7; int r = o >> 3;
    int n15 = r & 15; r >>= 4;
    int quad = r & 3; r >>= 2;
    int nt = r & 15; int kb = r >> 4;       // NT=16
    int k = kb * 32 + quad * 8 + j;
    int n = nt * 16 + n15;
    w2p[o] = f2bf(w2[(size_t)k * 256 + n]);
  }
}

// c1[j] += b1[j](blk0) + sum_{f in slice} (xh[f]+xp_b[f]) * w1[f,j]
// 16 blocks, each a 32-row f-slice; phase 1 reduces the 128 xh partials.
__global__ __launch_bounds__(256) void k_c1(const float* __restrict__ xhp,
                                            const float* __restrict__ xpb,
                                            const float* __restrict__ w1,
                                            const float* __restrict__ b1,
                                            float* __restrict__ c1) {
  const int bk = blockIdx.x;            // f-slice [bk*32, bk*32+32)
  __shared__ float xs[32];
  {
    const int f = threadIdx.x & 31;
    const int pg = threadIdx.x >> 5;    // 8 partial-groups
    float s = 0.f;
#pragma unroll 4
    for (int p = pg; p < 128; p += 8)
      s += xhp[(size_t)p * NFEAT + bk * 32 + f];
    __shared__ float red[256];
    red[threadIdx.x] = s;
    __syncthreads();
    if ((int)threadIdx.x < 32) {
      float t = 0.f;
#pragma unroll
      for (int g = 0; g < 8; ++g) t += red[g * 32 + threadIdx.x];
      xs[threadIdx.x] = t + xpb[bk * 32 + threadIdx.x];
    }
    __syncthreads();
  }
  const int j4 = threadIdx.x & 127;
  const int fp = threadIdx.x >> 7;
  float4 acc = {0.f, 0.f, 0.f, 0.f};
  const float4* w14 = (const float4*)w1;
#pragma unroll
  for (int ff = 0; ff < 16; ++ff) {
    const int f = bk * 32 + fp * 16 + ff;
    const float xv = xs[fp * 16 + ff];
    const float4 w = w14[(size_t)f * 128 + j4];
    acc.x += xv * w.x; acc.y += xv * w.y; acc.z += xv * w.z; acc.w += xv * w.w;
  }
  __shared__ float4 red2[128];
  if (fp) red2[j4] = acc;
  __syncthreads();
  if (!fp) {
    float4 o = red2[j4];
    o.x += acc.x; o.y += acc.y; o.z += acc.z; o.w += acc.w;
    if (bk == 0) {
      o.x += b1[j4 * 4 + 0]; o.y += b1[j4 * 4 + 1];
      o.z += b1[j4 * 4 + 2]; o.w += b1[j4 * 4 + 3];
    }
    atomicAdd(&c1[j4 * 4 + 0], o.x);
    atomicAdd(&c1[j4 * 4 + 1], o.y);
    atomicAdd(&c1[j4 * 4 + 2], o.z);
    atomicAdd(&c1[j4 * 4 + 3], o.w);
  }
}

// E1[896x512] = embb(bf16) @ w1p(bf16)  via mfma_f32_16x16x32_bf16
__global__ __launch_bounds__(256) void k_gemmE1(const short* __restrict__ embb,
                                                const short* __restrict__ w1p,
                                                float* __restrict__ E1) {
  const int lane = threadIdx.x & 63;
  const int wid = blockIdx.x * 4 + (threadIdx.x >> 6);
  const int n15 = lane & 15, quad = lane >> 4;
  const int mt = wid % MT;          // 0..55
  const int ng = wid / MT;          // 0..7
  const short* A = embb + (size_t)(mt * 16 + n15) * NFEAT + quad * 8;
  const short* Bbase = w1p + (ng * 16 + quad) * 128 + n15 * 8;
  v4f acc0 = {0.f,0.f,0.f,0.f}, acc1 = acc0, acc2 = acc0, acc3 = acc0;
#pragma unroll
  for (int kb = 0; kb < 16; ++kb) {
    v8s a = *(const v8s*)(A + kb * 32);
    const short* Bp = Bbase + (size_t)kb * 16384;   // kb*NT(32)*4*16*8
    v8s b0 = *(const v8s*)(Bp);
    v8s b1 = *(const v8s*)(Bp + 512);
    v8s b2 = *(const v8s*)(Bp + 1024);
    v8s b3 = *(const v8s*)(Bp + 1536);
    acc0 = __builtin_amdgcn_mfma_f32_16x16x32_bf16(a, b0, acc0, 0, 0, 0);
    acc1 = __builtin_amdgcn_mfma_f32_16x16x32_bf16(a, b1, acc1, 0, 0, 0);
    acc2 = __builtin_amdgcn_mfma_f32_16x16x32_bf16(a, b2, acc2, 0, 0, 0);
    acc3 = __builtin_amdgcn_mfma_f32_16x16x32_bf16(a, b3, acc3, 0, 0, 0);
  }
  float* C0 = E1 + (size_t)(mt * 16 + quad * 4) * NFEAT + ng * 64 + n15;
#pragma unroll
  for (int r = 0; r < 4; ++r) {
    C0[(size_t)r * NFEAT +  0] = acc0[r];
    C0[(size_t)r * NFEAT + 16] = acc1[r];
    C0[(size_t)r * NFEAT + 32] = acc2[r];
    C0[(size_t)r * NFEAT + 48] = acc3[r];
  }
}

// H2[871x256] = relu( relu(E1+c1)(bf16 on the fly) @ w2p + b2 )
__global__ __launch_bounds__(256) void k_gemmH2(const float* __restrict__ E1,
                                                const float* __restrict__ c1,
                                                const short* __restrict__ w2p,
                                                const float* __restrict__ b2,
                                                float* __restrict__ H2) {
  const int lane = threadIdx.x & 63;
  const int wid = blockIdx.x * 4 + (threadIdx.x >> 6);
  const int n15 = lane & 15, quad = lane >> 4;
  const int mt = wid % MT;          // 0..55
  const int ng = wid / MT;          // 0..3
  const float* Arow = E1 + (size_t)(mt * 16 + n15) * NFEAT + quad * 8;
  const short* Bbase = w2p + (ng * 16 + quad) * 128 + n15 * 8;
  v4f acc0 = {0.f,0.f,0.f,0.f}, acc1 = acc0, acc2 = acc0, acc3 = acc0;
#pragma unroll
  for (int kb = 0; kb < 16; ++kb) {
    float4 e0 = *(const float4*)(Arow + kb * 32);
    float4 e1 = *(const float4*)(Arow + kb * 32 + 4);
    float4 ca = *(const float4*)(c1 + kb * 32 + quad * 8);
    float4 cb = *(const float4*)(c1 + kb * 32 + quad * 8 + 4);
    v8s a;
    a[0] = f2bf(fmaxf(e0.x + ca.x, 0.f));
    a[1] = f2bf(fmaxf(e0.y + ca.y, 0.f));
    a[2] = f2bf(fmaxf(e0.z + ca.z, 0.f));
    a[3] = f2bf(fmaxf(e0.w + ca.w, 0.f));
    a[4] = f2bf(fmaxf(e1.x + cb.x, 0.f));
    a[5] = f2bf(fmaxf(e1.y + cb.y, 0.f));
    a[6] = f2bf(fmaxf(e1.z + cb.z, 0.f));
    a[7] = f2bf(fmaxf(e1.w + cb.w, 0.f));
    const short* Bp = Bbase + (size_t)kb * 8192;    // kb*NT(16)*4*16*8
    v8s b0 = *(const v8s*)(Bp);
    v8s b1 = *(const v8s*)(Bp + 512);
    v8s b2v = *(const v8s*)(Bp + 1024);
    v8s b3 = *(const v8s*)(Bp + 1536);
    acc0 = __builtin_amdgcn_mfma_f32_16x16x32_bf16(a, b0, acc0, 0, 0, 0);
    acc1 = __builtin_amdgcn_mfma_f32_16x16x32_bf16(a, b1, acc1, 0, 0, 0);
    acc2 = __builtin_amdgcn_mfma_f32_16x16x32_bf16(a, b2v, acc2, 0, 0, 0);
    acc3 = __builtin_amdgcn_mfma_f32_16x16x32_bf16(a, b3, acc3, 0, 0, 0);
  }
  const int grow0 = mt * 16 + quad * 4;
  const float bb0 = b2[ng * 64 + n15], bb1 = b2[ng * 64 + 16 + n15];
  const float bb2 = b2[ng * 64 + 32 + n15], bb3 = b2[ng * 64 + 48 + n15];
#pragma unroll
  for (int r = 0; r < 4; ++r) {
    const int grow = grow0 + r;
    if (grow < NNODE) {
      float* Hr = H2 + (size_t)grow * 256 + ng * 64 + n15;
      Hr[0]  = fmaxf(acc0[r] + bb0, 0.f);
      Hr[16] = fmaxf(acc1[r] + bb1, 0.f);
      Hr[32] = fmaxf(acc2[r] + bb2, 0.f);
      Hr[48] = fmaxf(acc3[r] + bb3, 0.f);
    }
  }
}

// v[i] = b3 + H2[i,:] . w3
__global__ void k_rowdot(const float* __restrict__ H2, const float* __restrict__ w3,
                         const float* __restrict__ b3, float* __restrict__ v) {
  const int wid = (blockIdx.x * 256 + threadIdx.x) >> 6;
  const int lane = threadIdx.x & 63;
  if (wid >= NNODE) return;
  float acc = 0.f;
  for (int j = lane; j < 256; j += 64) acc += H2[(size_t)wid * 256 + j] * w3[j];
  for (int off = 32; off > 0; off >>= 1) acc += __shfl_down(acc, off);
  if (lane == 0) v[wid] = acc + b3[0];
}

// loss = max(mean(v) - log(mean(exp(v))+1e-8), 0) + 0.1  (sum(softmax)==1 exactly)
__global__ void k_final(const float* __restrict__ ws, float* __restrict__ out) {
  const float* v = ws + WS_V;
  float s0 = 0.f, s1 = 0.f;
  for (int i = threadIdx.x; i < NNODE; i += 256) {
    float x = v[i];
    s0 += x;
    s1 += expf(x);
  }
  __shared__ float r0[256], r1[256];
  r0[threadIdx.x] = s0; r1[threadIdx.x] = s1;
  __syncthreads();
  for (int s = 128; s > 0; s >>= 1) {
    if ((int)threadIdx.x < s) {
      r0[threadIdx.x] += r0[threadIdx.x + s];
      r1[threadIdx.x] += r1[threadIdx.x + s];
    }
    __syncthreads();
  }
  if (threadIdx.x == 0) {
    float m0 = r0[0] / (float)NNODE;
    float m1 = r1[0] / (float)NNODE;
    float mi = m0 - logf(m1 + 1e-8f);
    out[ZPLANE] = fmaxf(mi, 0.f) + 0.1f;
  }
}

extern "C" void kernel_launch(void* const* d_in, const int* in_sizes, int n_in,
                              void* d_out, int out_size, void* d_ws, size_t ws_size,
                              hipStream_t stream) {
  const float* z   = (const float*)d_in[0];
  const float* x   = (const float*)d_in[1];
  const float* W   = (const float*)d_in[2];
  const float* b   = (const float*)d_in[3];
  const float* q   = (const float*)d_in[4];
  const float* xpw = (const float*)d_in[5];
  const float* xpb = (const float*)d_in[6];
  const float* w1  = (const float*)d_in[7];
  const float* b1  = (const float*)d_in[8];
  const float* w2  = (const float*)d_in[9];
  const float* b2  = (const float*)d_in[10];
  const float* w3  = (const float*)d_in[11];
  const float* b3  = (const float*)d_in[12];
  // d_in[13] (perm) unused: xh identical per row => permutation invariant under mean(exp(.)).
  float* out = (float*)d_out;
  float* ws  = (float*)d_ws;

  short* embb = (short*)(ws + WS_EMBB);
  short* w1p  = (short*)(ws + WS_W1P);
  short* w2p  = (short*)(ws + WS_W2P);

  k_init<<<17, 256, 0, stream>>>(ws);
  k_xh<<<128, 256, 0, stream>>>(x, xpw, ws + WS_XHP);
  k_conv<<<1536, 256, 0, stream>>>(w1, w2, w1p, w2p);
  k_scores<<<NMETA * NCHUNK, 256, 0, stream>>>(z, W, b, q, ws);
  k_emb<<<(Z4 + 255) / 256, 256, 0, stream>>>(z, ws, out, embb);
  k_c1<<<16, 256, 0, stream>>>(ws + WS_XHP, xpb, w1, b1, ws + WS_C1);
  k_gemmE1<<<112, 256, 0, stream>>>(embb, w1p, ws + WS_E1);
  k_gemmH2<<<56, 256, 0, stream>>>(ws + WS_E1, ws + WS_C1, w2p, b2, ws + WS_H2);
  k_rowdot<<<(NNODE + 3) / 4, 256, 0, stream>>>(ws + WS_H2, w3, b3, ws + WS_V);
  k_final<<<1, 256, 0, stream>>>(ws, out);
}

// Round 4
// 132.842 us; speedup vs baseline: 2.2660x; 1.1581x over previous
//
#include <hip/hip_runtime.h>
#include <hip/hip_bf16.h>
#include <math.h>

// ---- problem constants (hardcoded in reference) ----
#define NMETA  4
#define NNODE  871
#define NFEAT  512
#define XDIM   (116*116)            // 13456
#define ZPLANE (NNODE*NFEAT)        // 445952
#define Z4     (ZPLANE/4)           // 111488
#define NCHUNK 55                   // ceil(871/16)
#define MPAD   896                  // 56*16
#define MT     56

// ---- workspace layout (float offsets) ----
#define WS_SPART  16                 // [220] score partials (p*55+chunk)
#define WS_C1P    256                // [16*512] c1 partials (bk major)
#define WS_E1     8448               // [896*512] fp32 emb@w1[512:]
#define WS_XHP    WS_E1              // ALIAS [128*512] xh partials; dead before E1 written
#define WS_EMBB   467200             // bf16 [896][512] as shorts (229376 floats)
#define WS_V      696576             // [871]
#define WS_W1P    697448             // packed bf16 w1[512:1024] (131072 floats)
#define WS_W2P    828520             // packed bf16 w2 (32768 floats)

typedef short v8s __attribute__((ext_vector_type(8)));
typedef float v4f __attribute__((ext_vector_type(4)));

static __device__ __forceinline__ short f2bf(float f) {
  __hip_bfloat16 h = __float2bfloat16(f);
  return *reinterpret_cast<short*>(&h);
}

// ============ k_front: xh partials (128) | weight pack (1536) | score partials (220) ============
__global__ __launch_bounds__(256) void k_front(const float* __restrict__ x,
                                               const float* __restrict__ xpw,
                                               const float* __restrict__ w1,
                                               const float* __restrict__ w2,
                                               const float* __restrict__ z,
                                               const float* __restrict__ W,
                                               const float* __restrict__ b,
                                               const float* __restrict__ q,
                                               float* __restrict__ ws,
                                               short* __restrict__ w1p,
                                               short* __restrict__ w2p) {
  const int blk = blockIdx.x;
  const int tid = threadIdx.x;
  if (blk < 128) {
    // ---- xh partials: xhp[blk][f] = sum_{d in blk} x[d]*xp_w[d,f]
    const int f4 = tid & 127;
    const int rp = tid >> 7;
    const int d0 = blk * 106;
    const int rows = min(106, XDIM - d0);
    __shared__ float xs[106];
    if (tid < rows) xs[tid] = x[d0 + tid];
    __syncthreads();
    float4 acc = {0.f, 0.f, 0.f, 0.f};
    const float4* xp4 = (const float4*)xpw;
#pragma unroll 4
    for (int r = rp; r < rows; r += 2) {
      const float xv = xs[r];
      const float4 w = xp4[(size_t)(d0 + r) * 128 + f4];
      acc.x += xv * w.x; acc.y += xv * w.y; acc.z += xv * w.z; acc.w += xv * w.w;
    }
    __shared__ float4 red4[128];
    if (rp) red4[f4] = acc;
    __syncthreads();
    if (!rp) {
      float4 o = red4[f4];
      o.x += acc.x; o.y += acc.y; o.z += acc.z; o.w += acc.w;
      ((float4*)(ws + WS_XHP + (size_t)blk * NFEAT))[f4] = o;
    }
  } else if (blk < 128 + 1536) {
    // ---- pack w1[512:1024] and w2 into MFMA B-fragment order (bf16)
    int t = (blk - 128) * 256 + tid;
    if (t < 512 * 512) {
      int j = t & 7; int r = t >> 3;
      int n15 = r & 15; r >>= 4;
      int quad = r & 3; r >>= 2;
      int nt = r & 31; int kb = r >> 5;       // NT=32
      int k = kb * 32 + quad * 8 + j;
      int n = nt * 16 + n15;
      w1p[t] = f2bf(w1[(size_t)(512 + k) * 512 + n]);
    } else {
      int o = t - 512 * 512;                  // < 512*256 always (1536*256 = 393216 exactly)
      int j = o & 7; int r = o >> 3;
      int n15 = r & 15; r >>= 4;
      int quad = r & 3; r >>= 2;
      int nt = r & 15; int kb = r >> 4;       // NT=16
      int k = kb * 32 + quad * 8 + j;
      int n = nt * 16 + n15;
      w2p[o] = f2bf(w2[(size_t)k * 256 + n]);
    }
  } else {
    // ---- score partials: spart[p*55+chunk] (plain store, no atomics)
    const int sblk = blk - 1664;
    const int p = sblk / NCHUNK;
    const int chunk = sblk % NCHUNK;
    const int i0 = chunk * 16;
    const int i1 = min(i0 + 16, NNODE);
    const int f4 = tid & 127;
    const int ip = tid >> 7;
    float local = 0.f;
    for (int i = i0 + ip; i < i1; i += 2) {
      const float wi = W[i];
      const float bi = b[i];
      const float4 zr = ((const float4*)(z + ((size_t)p * NNODE + i) * NFEAT))[f4];
      const float4 qr = ((const float4*)(q + (size_t)i * NFEAT))[f4];
      local += tanhf(wi * zr.x + bi) * qr.x + tanhf(wi * zr.y + bi) * qr.y
             + tanhf(wi * zr.z + bi) * qr.z + tanhf(wi * zr.w + bi) * qr.w;
    }
    __shared__ float red[256];
    red[tid] = local;
    __syncthreads();
    for (int s = 128; s > 0; s >>= 1) {
      if (tid < s) red[tid] += red[tid + s];
      __syncthreads();
    }
    if (tid == 0) ws[WS_SPART + sblk] = red[0];
  }
}

// ============ k_mid: emb (448 blocks) | c1 partials + v zero (16 blocks) ============
__global__ __launch_bounds__(256) void k_mid(const float* __restrict__ z,
                                             float* __restrict__ ws,
                                             float* __restrict__ emb_out,
                                             short* __restrict__ embb,
                                             const float* __restrict__ xpb,
                                             const float* __restrict__ w1,
                                             const float* __restrict__ b1) {
  const int tid = threadIdx.x;
  if (blockIdx.x < 448) {
    // reduce score partials -> coef (per block, cheap)
    __shared__ float sp[220];
    __shared__ float sc[NMETA];
    if (tid < 220) sp[tid] = ws[WS_SPART + tid];
    __syncthreads();
    if (tid < NMETA) {
      float s = 0.f;
      for (int c = 0; c < NCHUNK; ++c) s += sp[tid * NCHUNK + c];
      sc[tid] = s;
    }
    __syncthreads();
    float sv[NMETA], sum = 0.f;
#pragma unroll
    for (int p = 0; p < NMETA; ++p) { sv[p] = sc[p] / (float)NNODE; sum += sv[p]; }
    float m = -1e30f;
#pragma unroll
    for (int p = 0; p < NMETA; ++p) { sv[p] = sv[p] / sum; m = fmaxf(m, sv[p]); }
    float es = 0.f;
#pragma unroll
    for (int p = 0; p < NMETA; ++p) { sv[p] = expf(sv[p] - m); es += sv[p]; }
    float coef[NMETA];
#pragma unroll
    for (int p = 0; p < NMETA; ++p) coef[p] = 1.f + sv[p] / es;

    const int idx = blockIdx.x * 256 + tid;   // < 448*256 = 114688 = MPAD*NFEAT/4
    if (idx < Z4) {
      const float4* z4 = (const float4*)z;
      float4 a = z4[idx];
      float4 bb = z4[Z4 + idx];
      float4 c = z4[2 * Z4 + idx];
      float4 d = z4[3 * Z4 + idx];
      float4 r;
      r.x = coef[0] * a.x + coef[1] * bb.x + coef[2] * c.x + coef[3] * d.x;
      r.y = coef[0] * a.y + coef[1] * bb.y + coef[2] * c.y + coef[3] * d.y;
      r.z = coef[0] * a.z + coef[1] * bb.z + coef[2] * c.z + coef[3] * d.z;
      r.w = coef[0] * a.w + coef[1] * bb.w + coef[2] * c.w + coef[3] * d.w;
      ((float4*)emb_out)[idx] = r;
      short4 h;
      h.x = f2bf(r.x); h.y = f2bf(r.y); h.z = f2bf(r.z); h.w = f2bf(r.w);
      ((short4*)embb)[idx] = h;
    } else {
      short4 zr = {0, 0, 0, 0};
      ((short4*)embb)[idx] = zr;              // pad rows 871..895
    }
  } else {
    const int bk = blockIdx.x - 448;          // f-slice [bk*32, bk*32+32)
    // zero v slice (16*55 >= 871)
    for (int t = tid; t < NCHUNK; t += 256) {
      int vi = bk * NCHUNK + t;
      if (vi < NNODE) ws[WS_V + vi] = 0.f;
    }
    __shared__ float xs[32];
    {
      const int f = tid & 31;
      const int pg = tid >> 5;
      float s = 0.f;
#pragma unroll 4
      for (int p = pg; p < 128; p += 8)
        s += ws[WS_XHP + (size_t)p * NFEAT + bk * 32 + f];
      __shared__ float red[256];
      red[tid] = s;
      __syncthreads();
      if (tid < 32) {
        float t2 = 0.f;
#pragma unroll
        for (int g = 0; g < 8; ++g) t2 += red[g * 32 + tid];
        xs[tid] = t2 + xpb[bk * 32 + tid];
      }
      __syncthreads();
    }
    const int j4 = tid & 127;
    const int fp = tid >> 7;
    float4 acc = {0.f, 0.f, 0.f, 0.f};
    const float4* w14 = (const float4*)w1;
#pragma unroll
    for (int ff = 0; ff < 16; ++ff) {
      const int f = bk * 32 + fp * 16 + ff;
      const float xv = xs[fp * 16 + ff];
      const float4 w = w14[(size_t)f * 128 + j4];
      acc.x += xv * w.x; acc.y += xv * w.y; acc.z += xv * w.z; acc.w += xv * w.w;
    }
    __shared__ float4 red2[128];
    if (fp) red2[j4] = acc;
    __syncthreads();
    if (!fp) {
      float4 o = red2[j4];
      o.x += acc.x; o.y += acc.y; o.z += acc.z; o.w += acc.w;
      if (bk == 0) {
        o.x += b1[j4 * 4 + 0]; o.y += b1[j4 * 4 + 1];
        o.z += b1[j4 * 4 + 2]; o.w += b1[j4 * 4 + 3];
      }
      ((float4*)(ws + WS_C1P + (size_t)bk * NFEAT))[j4] = o;  // plain store, no atomic
    }
  }
}

// ============ E1[896x512] = embb(bf16) @ w1p(bf16) ============
__global__ __launch_bounds__(256) void k_gemmE1(const short* __restrict__ embb,
                                                const short* __restrict__ w1p,
                                                float* __restrict__ E1) {
  const int lane = threadIdx.x & 63;
  const int wid = blockIdx.x * 4 + (threadIdx.x >> 6);
  const int n15 = lane & 15, quad = lane >> 4;
  const int mt = wid % MT;
  const int ng = wid / MT;
  const short* A = embb + (size_t)(mt * 16 + n15) * NFEAT + quad * 8;
  const short* Bbase = w1p + (ng * 16 + quad) * 128 + n15 * 8;
  v4f acc0 = {0.f,0.f,0.f,0.f}, acc1 = acc0, acc2 = acc0, acc3 = acc0;
#pragma unroll
  for (int kb = 0; kb < 16; ++kb) {
    v8s a = *(const v8s*)(A + kb * 32);
    const short* Bp = Bbase + (size_t)kb * 16384;
    v8s b0 = *(const v8s*)(Bp);
    v8s b1 = *(const v8s*)(Bp + 512);
    v8s b2 = *(const v8s*)(Bp + 1024);
    v8s b3 = *(const v8s*)(Bp + 1536);
    acc0 = __builtin_amdgcn_mfma_f32_16x16x32_bf16(a, b0, acc0, 0, 0, 0);
    acc1 = __builtin_amdgcn_mfma_f32_16x16x32_bf16(a, b1, acc1, 0, 0, 0);
    acc2 = __builtin_amdgcn_mfma_f32_16x16x32_bf16(a, b2, acc2, 0, 0, 0);
    acc3 = __builtin_amdgcn_mfma_f32_16x16x32_bf16(a, b3, acc3, 0, 0, 0);
  }
  float* C0 = E1 + (size_t)(mt * 16 + quad * 4) * NFEAT + ng * 64 + n15;
#pragma unroll
  for (int r = 0; r < 4; ++r) {
    C0[(size_t)r * NFEAT +  0] = acc0[r];
    C0[(size_t)r * NFEAT + 16] = acc1[r];
    C0[(size_t)r * NFEAT + 32] = acc2[r];
    C0[(size_t)r * NFEAT + 48] = acc3[r];
  }
}

// ============ H2 GEMM + fused rowdot: v[i] += relu(...)·w3 slice (H2 never stored) ============
__global__ __launch_bounds__(256) void k_gemmH2v(const float* __restrict__ E1,
                                                 const float* __restrict__ c1p,
                                                 const short* __restrict__ w2p,
                                                 const float* __restrict__ b2,
                                                 const float* __restrict__ w3,
                                                 float* __restrict__ v) {
  __shared__ float cs[512];
  {
    float a0 = 0.f, a1 = 0.f;
#pragma unroll
    for (int k = 0; k < 16; ++k) {
      a0 += c1p[(size_t)k * 512 + threadIdx.x];
      a1 += c1p[(size_t)k * 512 + 256 + threadIdx.x];
    }
    cs[threadIdx.x] = a0;
    cs[256 + threadIdx.x] = a1;
  }
  __syncthreads();
  const int lane = threadIdx.x & 63;
  const int wid = blockIdx.x * 4 + (threadIdx.x >> 6);
  const int n15 = lane & 15, quad = lane >> 4;
  const int mt = wid % MT;
  const int ng = wid / MT;
  const float* Arow = E1 + (size_t)(mt * 16 + n15) * NFEAT + quad * 8;
  const short* Bbase = w2p + (ng * 16 + quad) * 128 + n15 * 8;
  v4f acc0 = {0.f,0.f,0.f,0.f}, acc1 = acc0, acc2 = acc0, acc3 = acc0;
#pragma unroll
  for (int kb = 0; kb < 16; ++kb) {
    float4 e0 = *(const float4*)(Arow + kb * 32);
    float4 e1 = *(const float4*)(Arow + kb * 32 + 4);
    const float4 ca = *(const float4*)(cs + kb * 32 + quad * 8);
    const float4 cb = *(const float4*)(cs + kb * 32 + quad * 8 + 4);
    v8s a;
    a[0] = f2bf(fmaxf(e0.x + ca.x, 0.f));
    a[1] = f2bf(fmaxf(e0.y + ca.y, 0.f));
    a[2] = f2bf(fmaxf(e0.z + ca.z, 0.f));
    a[3] = f2bf(fmaxf(e0.w + ca.w, 0.f));
    a[4] = f2bf(fmaxf(e1.x + cb.x, 0.f));
    a[5] = f2bf(fmaxf(e1.y + cb.y, 0.f));
    a[6] = f2bf(fmaxf(e1.z + cb.z, 0.f));
    a[7] = f2bf(fmaxf(e1.w + cb.w, 0.f));
    const short* Bp = Bbase + (size_t)kb * 8192;
    v8s b0 = *(const v8s*)(Bp);
    v8s b1 = *(const v8s*)(Bp + 512);
    v8s b2v = *(const v8s*)(Bp + 1024);
    v8s b3 = *(const v8s*)(Bp + 1536);
    acc0 = __builtin_amdgcn_mfma_f32_16x16x32_bf16(a, b0, acc0, 0, 0, 0);
    acc1 = __builtin_amdgcn_mfma_f32_16x16x32_bf16(a, b1, acc1, 0, 0, 0);
    acc2 = __builtin_amdgcn_mfma_f32_16x16x32_bf16(a, b2v, acc2, 0, 0, 0);
    acc3 = __builtin_amdgcn_mfma_f32_16x16x32_bf16(a, b3, acc3, 0, 0, 0);
  }
  const float bb0 = b2[ng * 64 + n15],      bb1 = b2[ng * 64 + 16 + n15];
  const float bb2 = b2[ng * 64 + 32 + n15], bb3 = b2[ng * 64 + 48 + n15];
  const float w30 = w3[ng * 64 + n15],      w31 = w3[ng * 64 + 16 + n15];
  const float w32 = w3[ng * 64 + 32 + n15], w33 = w3[ng * 64 + 48 + n15];
  const int grow0 = mt * 16 + quad * 4;
#pragma unroll
  for (int r = 0; r < 4; ++r) {
    float s = fmaxf(acc0[r] + bb0, 0.f) * w30
            + fmaxf(acc1[r] + bb1, 0.f) * w31
            + fmaxf(acc2[r] + bb2, 0.f) * w32
            + fmaxf(acc3[r] + bb3, 0.f) * w33;
    s += __shfl_xor(s, 1);
    s += __shfl_xor(s, 2);
    s += __shfl_xor(s, 4);
    s += __shfl_xor(s, 8);
    const int grow = grow0 + r;
    if (n15 == 0 && grow < NNODE) atomicAdd(&v[grow], s);
  }
}

// ============ loss = max(mean(v+b3) - log(mean(exp(v+b3))+1e-8), 0) + 0.1 ============
__global__ void k_final(const float* __restrict__ ws, const float* __restrict__ b3,
                        float* __restrict__ out) {
  const float* v = ws + WS_V;
  const float bias = b3[0];
  float s0 = 0.f, s1 = 0.f;
  for (int i = threadIdx.x; i < NNODE; i += 256) {
    float x = v[i] + bias;
    s0 += x;
    s1 += expf(x);
  }
  __shared__ float r0[256], r1[256];
  r0[threadIdx.x] = s0; r1[threadIdx.x] = s1;
  __syncthreads();
  for (int s = 128; s > 0; s >>= 1) {
    if ((int)threadIdx.x < s) {
      r0[threadIdx.x] += r0[threadIdx.x + s];
      r1[threadIdx.x] += r1[threadIdx.x + s];
    }
    __syncthreads();
  }
  if (threadIdx.x == 0) {
    float m0 = r0[0] / (float)NNODE;
    float m1 = r1[0] / (float)NNODE;
    float mi = m0 - logf(m1 + 1e-8f);
    out[ZPLANE] = fmaxf(mi, 0.f) + 0.1f;   // sum(softmax)==1 exactly -> gamma term = 0.1
  }
}

extern "C" void kernel_launch(void* const* d_in, const int* in_sizes, int n_in,
                              void* d_out, int out_size, void* d_ws, size_t ws_size,
                              hipStream_t stream) {
  const float* z   = (const float*)d_in[0];
  const float* x   = (const float*)d_in[1];
  const float* W   = (const float*)d_in[2];
  const float* b   = (const float*)d_in[3];
  const float* q   = (const float*)d_in[4];
  const float* xpw = (const float*)d_in[5];
  const float* xpb = (const float*)d_in[6];
  const float* w1  = (const float*)d_in[7];
  const float* b1  = (const float*)d_in[8];
  const float* w2  = (const float*)d_in[9];
  const float* b2  = (const float*)d_in[10];
  const float* w3  = (const float*)d_in[11];
  const float* b3  = (const float*)d_in[12];
  // d_in[13] (perm) unused: xh identical per row => permutation invariant under mean(exp(.)).
  float* out = (float*)d_out;
  float* ws  = (float*)d_ws;

  short* embb = (short*)(ws + WS_EMBB);
  short* w1p  = (short*)(ws + WS_W1P);
  short* w2p  = (short*)(ws + WS_W2P);

  k_front<<<1884, 256, 0, stream>>>(x, xpw, w1, w2, z, W, b, q, ws, w1p, w2p);
  k_mid<<<464, 256, 0, stream>>>(z, ws, out, embb, xpb, w1, b1);
  k_gemmE1<<<112, 256, 0, stream>>>(embb, w1p, ws + WS_E1);
  k_gemmH2v<<<56, 256, 0, stream>>>(ws + WS_E1, ws + WS_C1P, w2p, b2, w3, ws + WS_V);
  k_final<<<1, 256, 0, stream>>>(ws, b3, out);
}